// Round 8
// baseline (81.539 us; speedup 1.0000x reference)
//
#include <hip/hip_runtime.h>
#include <float.h>

#define BB 16
#define CC 64
#define NN 2048
#define KNN 3
#define COUT 64
#define SPL 8   // candidate-range splits; 256 candidates/split -> 8-bit local idx

typedef _Float16 half8 __attribute__((ext_vector_type(8)));
typedef float f32x16 __attribute__((ext_vector_type(16)));

// ---------------------------------------------------------------------------
// K1: from x[b][c][n] produce:
//   xe[b][ct][kblk][lane] (16B fp16x8 MFMA fragments of ext=[hi|lo], K=128)
//   anc[b][ct][l<32] (packed fp16 pair (-nc/2 hi, -nc/2 lo))
// Fragment convention: row m = lane&31, k = kblk*16 + 8*(lane>>5) + j.
// kblk 0..3 = hi(x[c]) (c = k), kblk 4..7 = lo residual (c = k-64).
// ---------------------------------------------------------------------------
__global__ __launch_bounds__(256) void k_prep(const float* __restrict__ x,
                                              uint4* __restrict__ xe,
                                              unsigned* __restrict__ anc) {
    __shared__ float t[64][65];
    __shared__ float nsh[64];
    const int b = blockIdx.x;
    const int n0 = blockIdx.y * 64;
    const int tid = threadIdx.x;
    const int ln = tid & 63, g = tid >> 6;
#pragma unroll
    for (int i = 0; i < 16; ++i) {
        const int c = g + 4 * i;
        t[c][ln] = x[((size_t)b * CC + c) * NN + n0 + ln];
    }
    __syncthreads();
    if (tid < 64) {
        float s = 0.f;
#pragma unroll
        for (int c = 0; c < 64; ++c) s = fmaf(t[c][tid], t[c][tid], s);
        nsh[tid] = s;
    }
    // fragment packing: 1024 16B chunks per 64-point group
#pragma unroll
    for (int i = 0; i < 4; ++i) {
        const int cid = tid + 256 * i;
        const int lane = cid & 63;
        const int kblk = (cid >> 6) & 7;
        const int ctl = cid >> 9;               // 0..1
        const int m = ctl * 32 + (lane & 31);   // local point
        const int khalf = (lane >> 5) * 8;
        union { uint4 v; _Float16 h[8]; } pk;
#pragma unroll
        for (int j = 0; j < 8; ++j) {
            const int kg = kblk * 16 + khalf + j;
            const int ch = kg & 63;
            const float f = t[ch][m];
            const _Float16 hi = (_Float16)f;
            pk.h[j] = (kg < 64) ? hi : (_Float16)(f - (float)hi);
        }
        const int ct = (n0 >> 5) + ctl;
        xe[((size_t)(b * 64 + ct) * 8 + kblk) * 64 + lane] = pk.v;
    }
    __syncthreads();
    if (tid < 64) {
        const int ctl = tid >> 5, l = tid & 31;
        const int ct = (n0 >> 5) + ctl;
        const float h = -0.5f * nsh[ctl * 32 + l];
        const _Float16 a0 = (_Float16)h;
        const _Float16 a1 = (_Float16)(h - (float)a0);
        union { unsigned u; _Float16 hh[2]; } cu;
        cu.hh[0] = a0; cu.hh[1] = a1;
        anc[(size_t)(b * 64 + ct) * 32 + l] = cu.u;
    }
}

// ---------------------------------------------------------------------------
// K1b: pack W into fp16 B-fragments. Wf[((kk*2+ct2)*4+kb)*64 + lane]:
// co = ct2*32 + (lane&31), c = kb*16 + 8*(lane>>5) + j, value = fp16(W[co][c][kk])
// ---------------------------------------------------------------------------
__global__ __launch_bounds__(256) void k_wprep(const float* __restrict__ W,
                                               uint4* __restrict__ Wf) {
    const int tid = threadIdx.x;
#pragma unroll
    for (int i = 0; i < 6; ++i) {
        const int id = tid + 256 * i;
        const int l = id & 63;
        const int kb = (id >> 6) & 3;
        const int ct2 = (id >> 8) & 1;
        const int kk = id >> 9;
        const int co = ct2 * 32 + (l & 31);
        union { uint4 v; _Float16 h[8]; } pk;
#pragma unroll
        for (int j = 0; j < 8; ++j) {
            const int c = kb * 16 + 8 * (l >> 5) + j;
            pk.h[j] = (_Float16)W[(co * CC + c) * KNN + kk];
        }
        Wf[id] = pk.v;
    }
}

// ---------------------------------------------------------------------------
// K2: MFMA top-3, QG=2. Wave = 64 queries (2 B-operand groups, resident);
// loops 8 candidate tiles; each af tile-load feeds BOTH accumulators
// (34 MFMA per 8 loads). Rank by LARGEST acc = dot - nc/2.
// Result per (q, split): uint4 {key0,key1,key2, LOCAL i0|i1<<8|i2<<16}
// (local = global - s*256, 0..255 -> 24 bits, no overflow).
// ---------------------------------------------------------------------------
__global__ __launch_bounds__(256, 2) void k_top3(const half8* __restrict__ xe,
                                                 const unsigned* __restrict__ anc,
                                                 uint4* __restrict__ pk) {
    const int tid = threadIdx.x;
    const int lane = tid & 63;
    const int wq = blockIdx.x * 4 + (tid >> 6);  // 0..31
    const int qgA = wq * 2, qgB = wq * 2 + 1;
    const int s = blockIdx.y;
    const int b = blockIdx.z;

    half8 bqA[8], bqB[8];
#pragma unroll
    for (int kb = 0; kb < 8; ++kb) {
        bqA[kb] = xe[((size_t)(b * 64 + qgA) * 8 + kb) * 64 + lane];
        bqB[kb] = xe[((size_t)(b * 64 + qgB) * 8 + kb) * 64 + lane];
    }
    half8 bnc = {};
    if (lane < 32) { bnc[0] = (_Float16)1.0f; bnc[1] = (_Float16)1.0f; }

    float kA0 = -FLT_MAX, kA1 = -FLT_MAX, kA2 = -FLT_MAX;
    float kB0 = -FLT_MAX, kB1 = -FLT_MAX, kB2 = -FLT_MAX;
    int iA0 = -1, iA1 = -1, iA2 = -1;
    int iB0 = -1, iB1 = -1, iB2 = -1;
    const int hi4 = (lane >> 5) * 4;

    constexpr int TILES = NN / 32 / SPL;  // 8
    const int ct0 = s * TILES;
    for (int t = 0; t < TILES; ++t) {
        const int ct = ct0 + t;
        half8 af[8];
#pragma unroll
        for (int kb = 0; kb < 8; ++kb)
            af[kb] = xe[((size_t)(b * 64 + ct) * 8 + kb) * 64 + lane];
        half8 av = {};
        {
            union { unsigned u; _Float16 hh[2]; } cu;
            cu.u = anc[(size_t)(b * 64 + ct) * 32 + (lane & 31)];
            av[0] = cu.hh[0]; av[1] = cu.hh[1];
        }
        f32x16 accA = {}, accB = {};
#pragma unroll
        for (int kb = 0; kb < 8; ++kb) {  // hihi + lolo
            accA = __builtin_amdgcn_mfma_f32_32x32x16_f16(af[kb], bqA[kb], accA, 0, 0, 0);
            accB = __builtin_amdgcn_mfma_f32_32x32x16_f16(af[kb], bqB[kb], accB, 0, 0, 0);
        }
#pragma unroll
        for (int kb = 0; kb < 8; ++kb) {  // hilo + lohi
            accA = __builtin_amdgcn_mfma_f32_32x32x16_f16(af[kb], bqA[(kb + 4) & 7], accA, 0, 0, 0);
            accB = __builtin_amdgcn_mfma_f32_32x32x16_f16(af[kb], bqB[(kb + 4) & 7], accB, 0, 0, 0);
        }
        accA = __builtin_amdgcn_mfma_f32_32x32x16_f16(av, bnc, accA, 0, 0, 0);
        accB = __builtin_amdgcn_mfma_f32_32x32x16_f16(av, bnc, accB, 0, 0, 0);

        const int mbase = t * 32 + hi4;  // LOCAL index within the split
#pragma unroll
        for (int j = 0; j < 16; ++j) {
            const float a = accA[j];
            if (__any(a > kA2)) {
                const int m = mbase + (j & 3) + 8 * (j >> 2);
                const bool g0 = a > kA0, g1 = a > kA1, g2 = a > kA2;
                kA2 = g1 ? kA1 : (g2 ? a : kA2); iA2 = g1 ? iA1 : (g2 ? m : iA2);
                kA1 = g0 ? kA0 : (g1 ? a : kA1); iA1 = g0 ? iA0 : (g1 ? m : iA1);
                kA0 = g0 ? a : kA0;              iA0 = g0 ? m : iA0;
            }
        }
#pragma unroll
        for (int j = 0; j < 16; ++j) {
            const float a = accB[j];
            if (__any(a > kB2)) {
                const int m = mbase + (j & 3) + 8 * (j >> 2);
                const bool g0 = a > kB0, g1 = a > kB1, g2 = a > kB2;
                kB2 = g1 ? kB1 : (g2 ? a : kB2); iB2 = g1 ? iB1 : (g2 ? m : iB2);
                kB1 = g0 ? kB0 : (g1 ? a : kB1); iB1 = g0 ? iB0 : (g1 ? m : iB1);
                kB0 = g0 ? a : kB0;              iB0 = g0 ? m : iB0;
            }
        }
    }

    // per-group: merge lane-halves (disjoint candidates) lexicographically, store
#pragma unroll
    for (int grp = 0; grp < 2; ++grp) {
        float K0 = grp ? kB0 : kA0, K1 = grp ? kB1 : kA1, K2 = grp ? kB2 : kA2;
        int I0 = grp ? iB0 : iA0, I1 = grp ? iB1 : iA1, I2 = grp ? iB2 : iA2;
        const float ok0 = __shfl_xor(K0, 32), ok1 = __shfl_xor(K1, 32), ok2 = __shfl_xor(K2, 32);
        const int oi0 = __shfl_xor(I0, 32), oi1 = __shfl_xor(I1, 32), oi2 = __shfl_xor(I2, 32);
        const float ck[3] = {ok0, ok1, ok2};
        const int cix[3] = {oi0, oi1, oi2};
#pragma unroll
        for (int r = 0; r < 3; ++r) {
            const float c = ck[r]; const int ci = cix[r];
            const bool b0 = (c > K0) || (c == K0 && ci < I0);
            const bool b1 = (c > K1) || (c == K1 && ci < I1);
            const bool b2 = (c > K2) || (c == K2 && ci < I2);
            K2 = b1 ? K1 : (b2 ? c : K2); I2 = b1 ? I1 : (b2 ? ci : I2);
            K1 = b0 ? K0 : (b1 ? c : K1); I1 = b0 ? I0 : (b1 ? ci : I1);
            K0 = b0 ? c : K0;             I0 = b0 ? ci : I0;
        }
        if (lane < 32) {
            const int q = (grp ? qgB : qgA) * 32 + lane;
            uint4 v;
            v.x = __float_as_uint(K0);
            v.y = __float_as_uint(K1);
            v.z = __float_as_uint(K2);
            v.w = (unsigned)I0 | ((unsigned)I1 << 8) | ((unsigned)I2 << 16);
            pk[((size_t)b * SPL + s) * NN + q] = v;
        }
    }
}

// ---------------------------------------------------------------------------
// K3: merge SPL packed top-3 lists, (key desc, global idx asc) lexicographic.
// Global idx = local (8-bit) + s*256.
// ---------------------------------------------------------------------------
__global__ __launch_bounds__(256) void k_merge(const uint4* __restrict__ pk,
                                               int* __restrict__ fi) {
    const int t = blockIdx.x * 256 + threadIdx.x;
    if (t >= BB * NN) return;
    const int b = t / NN, n = t % NN;
    float dv[3 * SPL]; int iv[3 * SPL];
#pragma unroll
    for (int s = 0; s < SPL; ++s) {
        const uint4 v = pk[((size_t)b * SPL + s) * NN + n];
        dv[s * 3 + 0] = __uint_as_float(v.x);
        dv[s * 3 + 1] = __uint_as_float(v.y);
        dv[s * 3 + 2] = __uint_as_float(v.z);
        iv[s * 3 + 0] = (int)(v.w & 255u) + s * 256;
        iv[s * 3 + 1] = (int)((v.w >> 8) & 255u) + s * 256;
        iv[s * 3 + 2] = (int)((v.w >> 16) & 255u) + s * 256;
    }
    float bd = FLT_MAX; int bi = -1;
#pragma unroll
    for (int r = 0; r < 3; ++r) {
        float ck = -FLT_MAX; int ci = 0x7fffffff;
#pragma unroll
        for (int j = 0; j < 3 * SPL; ++j) {
            const bool after_prev = (dv[j] < bd) || (dv[j] == bd && iv[j] > bi);
            const bool better = (dv[j] > ck) || (dv[j] == ck && iv[j] < ci);
            if (after_prev && better) { ck = dv[j]; ci = iv[j]; }
        }
        fi[(size_t)t * 3 + r] = ci;
        bd = ck; bi = ci;
    }
}

// ---------------------------------------------------------------------------
// K4: MFMA conv. Block = 64 points x 64 co, 4 waves. A = gathered hi-fp16
// fragments straight from xe (kb 0..3), B = pre-packed Wf.
// Epilogue: bias + relu -> padded LDS transpose -> coalesced stores.
// ---------------------------------------------------------------------------
__global__ __launch_bounds__(256) void k_conv(const uint4* __restrict__ xe,
                                              const uint4* __restrict__ Wf,
                                              const int* __restrict__ fi,
                                              const float* __restrict__ bias,
                                              float* __restrict__ out) {
    __shared__ float ot[64][65];
    const int b = blockIdx.y;
    const int n0 = blockIdx.x * 64;
    const int tid = threadIdx.x;
    const int l = tid & 63;
    const int w = tid >> 6;
    const int mt = w >> 1, ct2 = w & 1;
    const int p31 = l & 31, kh = l >> 5;
    const int npt = n0 + mt * 32 + p31;

    f32x16 acc = {};
    const uint4* xb = xe + (size_t)b * 64 * 8 * 64;
    const int fbase3 = (b * NN + npt) * KNN;
#pragma unroll
    for (int kk = 0; kk < KNN; ++kk) {
        const int src = fi[fbase3 + kk];
        const uint4* ap = xb + (size_t)(src >> 5) * 512 + (src & 31) + 32 * kh;
        uint4 af[4], bw[4];
#pragma unroll
        for (int kb = 0; kb < 4; ++kb) af[kb] = ap[(size_t)kb * 64];
#pragma unroll
        for (int kb = 0; kb < 4; ++kb) bw[kb] = Wf[((kk * 2 + ct2) * 4 + kb) * 64 + l];
#pragma unroll
        for (int kb = 0; kb < 4; ++kb) {
            union { uint4 v; half8 h; } ua, ub;
            ua.v = af[kb]; ub.v = bw[kb];
            acc = __builtin_amdgcn_mfma_f32_32x32x16_f16(ua.h, ub.h, acc, 0, 0, 0);
        }
    }
    const int co = ct2 * 32 + p31;
    const float bv = bias[co];
#pragma unroll
    for (int j = 0; j < 16; ++j) {
        const int pt = mt * 32 + (j & 3) + 8 * (j >> 2) + 4 * kh;
        ot[co][pt] = fmaxf(acc[j] + bv, 0.f);
    }
    __syncthreads();
#pragma unroll
    for (int i = 0; i < 16; ++i) {
        const int v = tid + 256 * i;
        const int co2 = v >> 6, col = v & 63;
        out[((size_t)(b * COUT + co2)) * NN + n0 + col] = ot[co2][col];
    }
}

extern "C" void kernel_launch(void* const* d_in, const int* in_sizes, int n_in,
                              void* d_out, int out_size, void* d_ws, size_t ws_size,
                              hipStream_t stream) {
    const float* x = (const float*)d_in[0];
    const float* W = (const float*)d_in[1];
    const float* bias = (const float*)d_in[2];
    float* out = (float*)d_out;

    char* ws = (char*)d_ws;
    uint4* xe = (uint4*)(ws);                       //  8,388,608 B
    unsigned* anc = (unsigned*)(ws + 8388608);      //    131,072 B
    uint4* Wf = (uint4*)(ws + 8519680);             //     24,576 B
    uint4* pk = (uint4*)(ws + 8544256);             //  4,194,304 B
    int* fi = (int*)(ws + 12738560);                //    393,216 B (end ~13.1 MB)

    k_prep<<<dim3(BB, NN / 64), 256, 0, stream>>>(x, xe, anc);
    k_wprep<<<1, 256, 0, stream>>>(W, Wf);
    k_top3<<<dim3(8, SPL, BB), 256, 0, stream>>>((const half8*)xe, anc, pk);
    k_merge<<<(BB * NN + 255) / 256, 256, 0, stream>>>(pk, fi);
    k_conv<<<dim3(NN / 64, BB), 256, 0, stream>>>(xe, Wf, fi, bias, out);
}